// Round 6
// baseline (194.369 us; speedup 1.0000x reference)
//
#include <hip/hip_runtime.h>
#include <math.h>

#define LN_EPS 1e-5f
#define LOG2E  1.44269504088896340736f

typedef float vf4 __attribute__((ext_vector_type(4)));

// ============================================================================
// Math (derived, exact):
//  - softmin cancels out of LayerNorm entirely (shift invariance; best <= min x).
//  - h_i = (mu - x_i)*rsqrt(var+eps)*lnw_i + lnb_i, and since sum(d_i) = 0,
//    layer1 pre-activation a_j = A0_j*t0 + A1_j*t1 + C_j with t_i = d_i*rs.
//  - relu(u + C) = max(u, -C) + C ; the "+C" term folds into b2 via sum_j w2*C.
//  - log2e folds into w2,b2 so softmax uses exp2 (v_exp_f32) directly, no
//    max-subtract (|logits| <~ 25 in log2 domain, far from overflow).
// ws layout (floats): A0[0..15] A1[16..31] negC[32..47]
//                     W2s[48+16c+j] (c<3,j<16)  B2s[96..98]
//
// R6 structure: 4 rows/thread, __launch_bounds__(256,8) -> <=64 VGPR ->
// 8 waves/SIMD for latency hiding. Cached loads (lines shared across the
// thread's 3 strided dwordx4), NT stores only.
// ============================================================================

__global__ void nn2_setup(const float* __restrict__ lnw, const float* __restrict__ lnb,
                          const float* __restrict__ w1,  const float* __restrict__ b1,
                          const float* __restrict__ w2,  const float* __restrict__ b2,
                          float* __restrict__ ws)
{
    int t = threadIdx.x;
    if (t < 16) {
        float lw0 = lnw[0], lw1 = lnw[1], lw2 = lnw[2];
        float lb0 = lnb[0], lb1 = lnb[1], lb2 = lnb[2];
        float w10 = w1[3*t], w11 = w1[3*t+1], w12 = w1[3*t+2];
        ws[t]    = w10 * lw0 - w12 * lw2;
        ws[16+t] = w11 * lw1 - w12 * lw2;
        ws[32+t] = -(w10 * lb0 + w11 * lb1 + w12 * lb2 + b1[t]);
    }
    if (t < 48) ws[48+t] = w2[t] * LOG2E;
    if (t < 3) {
        float lb0 = lnb[0], lb1 = lnb[1], lb2 = lnb[2];
        float acc = b2[t];
        for (int j = 0; j < 16; ++j) {
            float c = w1[3*j]*lb0 + w1[3*j+1]*lb1 + w1[3*j+2]*lb2 + b1[j];
            acc = fmaf(w2[16*t+j], c, acc);
        }
        ws[96+t] = acc * LOG2E;
    }
}

__global__ __launch_bounds__(256, 8) void nn2_main(
    const float* __restrict__ x, const float* __restrict__ ws,
    float* __restrict__ out, int nrows)
{
    int g = blockIdx.x * blockDim.x + threadIdx.x;
    long long base = (long long)g * 4;
    if (base >= nrows) return;
    const bool full = (base + 4 <= nrows);

    // ---- load 4 rows (3x dwordx4, 48B contiguous per thread, cached) ----
    float X[4][3];
    if (full) {
        const vf4* x4 = reinterpret_cast<const vf4*>(x) + (long long)g * 3;
        vf4 va = x4[0], vb = x4[1], vc = x4[2];
        X[0][0]=va.x; X[0][1]=va.y; X[0][2]=va.z;
        X[1][0]=va.w; X[1][1]=vb.x; X[1][2]=vb.y;
        X[2][0]=vb.z; X[2][1]=vb.w; X[2][2]=vc.x;
        X[3][0]=vc.y; X[3][1]=vc.z; X[3][2]=vc.w;
    } else {
#pragma unroll
        for (int r = 0; r < 4; ++r) {
            long long rr = (base + r < nrows) ? base + r : (long long)nrows - 1;
            X[r][0]=x[rr*3]; X[r][1]=x[rr*3+1]; X[r][2]=x[rr*3+2];
        }
    }

    // ---- LayerNorm core: t0,t1 per row ----
    float t0[4], t1[4];
#pragma unroll
    for (int r = 0; r < 4; ++r) {
        float x0 = X[r][0], x1 = X[r][1], x2 = X[r][2];
        float mu = (x0 + x1 + x2) * (1.0f/3.0f);
        float d0 = mu - x0, d1 = mu - x1, d2 = mu - x2;
        float sse = fmaf(d0, d0, fmaf(d1, d1, d2 * d2));
        float rs  = __builtin_amdgcn_rsqf(fmaf(sse, 1.0f/3.0f, LN_EPS));
        t0[r] = d0 * rs;
        t1[r] = d1 * rs;
    }

    // ---- fused MLP: logits in log2 domain ----
    float l[4][3];
    {
        const float B0 = ws[96], B1 = ws[97], B2 = ws[98];
#pragma unroll
        for (int r = 0; r < 4; ++r) { l[r][0] = B0; l[r][1] = B1; l[r][2] = B2; }
    }
#pragma unroll
    for (int j = 0; j < 16; ++j) {
        const float A0 = ws[j];
        const float A1 = ws[16+j];
        const float nC = ws[32+j];
        const float u0 = ws[48+j];
        const float u1 = ws[64+j];
        const float u2 = ws[80+j];
#pragma unroll
        for (int r = 0; r < 4; ++r) {
            float a = fmaf(A1, t1[r], A0 * t0[r]);
            float m = fmaxf(a, nC);
            l[r][0] = fmaf(m, u0, l[r][0]);
            l[r][1] = fmaf(m, u1, l[r][1]);
            l[r][2] = fmaf(m, u2, l[r][2]);
        }
    }

    // ---- softmax (exp2, no max-subtract) + weighted sum ----
    float O[4];
#pragma unroll
    for (int r = 0; r < 4; ++r) {
        float e0 = __builtin_amdgcn_exp2f(l[r][0]);
        float e1 = __builtin_amdgcn_exp2f(l[r][1]);
        float e2 = __builtin_amdgcn_exp2f(l[r][2]);
        float rc = __builtin_amdgcn_rcpf(e0 + e1 + e2);
        O[r] = fmaf(X[r][0], e0, fmaf(X[r][1], e1, X[r][2] * e2)) * rc;
    }

    if (full) {
        vf4 o; o.x=O[0]; o.y=O[1]; o.z=O[2]; o.w=O[3];
        __builtin_nontemporal_store(o, &reinterpret_cast<vf4*>(out)[g]);
    } else {
        for (int r = 0; r < 4 && base + r < nrows; ++r) out[base + r] = O[r];
    }
}

// Fallback (ws too small): self-contained, weights via point-of-use s_loads.
__global__ __launch_bounds__(256) void nn2_fallback(
    const float* __restrict__ x,
    const float* __restrict__ lnw_g, const float* __restrict__ lnb_g,
    const float* __restrict__ w1_g,  const float* __restrict__ b1_g,
    const float* __restrict__ w2_g,  const float* __restrict__ b2_g,
    float* __restrict__ out, int nrows)
{
    int g = blockIdx.x * blockDim.x + threadIdx.x;
    long long base = (long long)g * 4;
    if (base >= nrows) return;
    const float lw0 = lnw_g[0], lw1 = lnw_g[1], lw2 = lnw_g[2];
    const float lb0 = lnb_g[0], lb1 = lnb_g[1], lb2 = lnb_g[2];
    float X[4][3];
    if (base + 4 <= nrows) {
        const float4* x4 = reinterpret_cast<const float4*>(x) + (long long)g * 3;
        float4 va = x4[0], vb = x4[1], vc = x4[2];
        X[0][0]=va.x; X[0][1]=va.y; X[0][2]=va.z;
        X[1][0]=va.w; X[1][1]=vb.x; X[1][2]=vb.y;
        X[2][0]=vb.z; X[2][1]=vb.w; X[2][2]=vc.x;
        X[3][0]=vc.y; X[3][1]=vc.z; X[3][2]=vc.w;
    } else {
        for (int r = 0; r < 4; ++r) {
            long long rr = (base + r < nrows) ? base + r : (long long)nrows - 1;
            X[r][0]=x[rr*3]; X[r][1]=x[rr*3+1]; X[r][2]=x[rr*3+2];
        }
    }
    float H[4][3];
#pragma unroll
    for (int r = 0; r < 4; ++r) {
        float x0=X[r][0], x1=X[r][1], x2=X[r][2];
        float mu=(x0+x1+x2)*(1.0f/3.0f);
        float d0=mu-x0, d1=mu-x1, d2=mu-x2;
        float rs=__builtin_amdgcn_rsqf(fmaf(fmaf(d0,d0,fmaf(d1,d1,d2*d2)),1.0f/3.0f,LN_EPS));
        H[r][0]=fmaf(d0*rs,lw0,lb0); H[r][1]=fmaf(d1*rs,lw1,lb1); H[r][2]=fmaf(d2*rs,lw2,lb2);
    }
    float L[4][3];
    { const float b20=b2_g[0],b21=b2_g[1],b22=b2_g[2];
#pragma unroll
      for (int r=0;r<4;++r){L[r][0]=b20;L[r][1]=b21;L[r][2]=b22;} }
#pragma unroll
    for (int j = 0; j < 16; ++j) {
        const float a0=w1_g[3*j],a1=w1_g[3*j+1],a2=w1_g[3*j+2],bj=b1_g[j];
        const float u0=w2_g[j],u1=w2_g[16+j],u2=w2_g[32+j];
#pragma unroll
        for (int r=0;r<4;++r){
            float hj=fmaf(H[r][2],a2,fmaf(H[r][1],a1,fmaf(H[r][0],a0,bj)));
            hj=fmaxf(hj,0.0f);
            L[r][0]=fmaf(hj,u0,L[r][0]); L[r][1]=fmaf(hj,u1,L[r][1]); L[r][2]=fmaf(hj,u2,L[r][2]);
        }
    }
    float O[4];
#pragma unroll
    for (int r=0;r<4;++r){
        float l0=L[r][0],l1=L[r][1],l2=L[r][2];
        float lm=fmaxf(l0,fmaxf(l1,l2));
        float s0=__expf(l0-lm),s1=__expf(l1-lm),s2=__expf(l2-lm);
        float rc=__builtin_amdgcn_rcpf(s0+s1+s2);
        O[r]=fmaf(X[r][0],s0,fmaf(X[r][1],s1,X[r][2]*s2))*rc;
    }
    if (base + 4 <= nrows) {
        float4 o; o.x=O[0];o.y=O[1];o.z=O[2];o.w=O[3];
        reinterpret_cast<float4*>(out)[g] = o;
    } else {
        for (int r = 0; r < 4 && base + r < nrows; ++r) out[base + r] = O[r];
    }
}

extern "C" void kernel_launch(void* const* d_in, const int* in_sizes, int n_in,
                              void* d_out, int out_size, void* d_ws, size_t ws_size,
                              hipStream_t stream) {
    const float* x    = (const float*)d_in[0];
    const float* lnw  = (const float*)d_in[1];
    const float* lnb  = (const float*)d_in[2];
    const float* w1   = (const float*)d_in[3];
    const float* b1   = (const float*)d_in[4];
    const float* w2   = (const float*)d_in[5];
    const float* b2   = (const float*)d_in[6];
    // d_in[7] (log_tau) is mathematically dead: softmin cancels in LayerNorm.
    float* out = (float*)d_out;
    int nrows = out_size;

    if (ws_size >= 99 * sizeof(float)) {
        float* ws = (float*)d_ws;
        nn2_setup<<<1, 64, 0, stream>>>(lnw, lnb, w1, b1, w2, b2, ws);
        int T    = (nrows + 3) / 4;            // 4 rows per thread
        int grid = (T + 255) / 256;
        nn2_main<<<grid, 256, 0, stream>>>(x, ws, out, nrows);
    } else {
        int ngroups = (nrows + 3) / 4;
        int grid    = (ngroups + 255) / 256;
        nn2_fallback<<<grid, 256, 0, stream>>>(x, lnw, lnb, w1, b1, w2, b2, out, nrows);
    }
}

// Round 7
// 65.387 us; speedup vs baseline: 2.9726x; 2.9726x over previous
//
#include <hip/hip_runtime.h>
#include <math.h>

#define LN_EPS 1e-5f
#define LOG2E  1.44269504088896340736f

typedef float vf4 __attribute__((ext_vector_type(4)));

// ============================================================================
// Math (derived, exact):
//  - softmin cancels out of LayerNorm entirely (shift invariance; best <= min x).
//  - h_i = (mu - x_i)*rsqrt(var+eps)*lnw_i + lnb_i, and since sum(d_i) = 0,
//    layer1 pre-activation a_j = A0_j*t0 + A1_j*t1 + C_j with t_i = d_i*rs.
//  - relu(u + C) = max(u, -C) + C ; the "+C" term folds into b2 via sum_j w2*C.
//  - log2e folds into w2,b2 so softmax uses exp2 (v_exp_f32) directly, no
//    max-subtract (|logits| <~ 25 in log2 domain, far from overflow).
// ws layout (floats): A0[0..15] A1[16..31] negC[32..47]
//                     W2s[48+16c+j] (c<3,j<16)  B2s[96..98]
//
// R7 structure: R3's proven shape — 4 rows/thread, plain launch_bounds(256),
// natural VGPR allocation (NO min-waves quota: R6 showed the allocator meets
// a quota by spilling). Cached loads; NT store only (no-allocate stores keep
// x L3-resident across graph replays).
// ============================================================================

__global__ void nn2_setup(const float* __restrict__ lnw, const float* __restrict__ lnb,
                          const float* __restrict__ w1,  const float* __restrict__ b1,
                          const float* __restrict__ w2,  const float* __restrict__ b2,
                          float* __restrict__ ws)
{
    int t = threadIdx.x;
    if (t < 16) {
        float lw0 = lnw[0], lw1 = lnw[1], lw2 = lnw[2];
        float lb0 = lnb[0], lb1 = lnb[1], lb2 = lnb[2];
        float w10 = w1[3*t], w11 = w1[3*t+1], w12 = w1[3*t+2];
        ws[t]    = w10 * lw0 - w12 * lw2;
        ws[16+t] = w11 * lw1 - w12 * lw2;
        ws[32+t] = -(w10 * lb0 + w11 * lb1 + w12 * lb2 + b1[t]);
    }
    if (t < 48) ws[48+t] = w2[t] * LOG2E;
    if (t < 3) {
        float lb0 = lnb[0], lb1 = lnb[1], lb2 = lnb[2];
        float acc = b2[t];
        for (int j = 0; j < 16; ++j) {
            float c = w1[3*j]*lb0 + w1[3*j+1]*lb1 + w1[3*j+2]*lb2 + b1[j];
            acc = fmaf(w2[16*t+j], c, acc);
        }
        ws[96+t] = acc * LOG2E;
    }
}

__global__ __launch_bounds__(256) void nn2_main(
    const float* __restrict__ x, const float* __restrict__ ws,
    float* __restrict__ out, int nrows)
{
    int g = blockIdx.x * blockDim.x + threadIdx.x;
    long long base = (long long)g * 4;
    if (base >= nrows) return;
    const bool full = (base + 4 <= nrows);

    // ---- load 4 rows (3x dwordx4, 48B contiguous per thread, cached) ----
    float X[4][3];
    if (full) {
        const vf4* x4 = reinterpret_cast<const vf4*>(x) + (long long)g * 3;
        vf4 va = x4[0], vb = x4[1], vc = x4[2];
        X[0][0]=va.x; X[0][1]=va.y; X[0][2]=va.z;
        X[1][0]=va.w; X[1][1]=vb.x; X[1][2]=vb.y;
        X[2][0]=vb.z; X[2][1]=vb.w; X[2][2]=vc.x;
        X[3][0]=vc.y; X[3][1]=vc.z; X[3][2]=vc.w;
    } else {
#pragma unroll
        for (int r = 0; r < 4; ++r) {
            long long rr = (base + r < nrows) ? base + r : (long long)nrows - 1;
            X[r][0]=x[rr*3]; X[r][1]=x[rr*3+1]; X[r][2]=x[rr*3+2];
        }
    }

    // ---- LayerNorm core: t0,t1 per row ----
    float t0[4], t1[4];
#pragma unroll
    for (int r = 0; r < 4; ++r) {
        float x0 = X[r][0], x1 = X[r][1], x2 = X[r][2];
        float mu = (x0 + x1 + x2) * (1.0f/3.0f);
        float d0 = mu - x0, d1 = mu - x1, d2 = mu - x2;
        float sse = fmaf(d0, d0, fmaf(d1, d1, d2 * d2));
        float rs  = __builtin_amdgcn_rsqf(fmaf(sse, 1.0f/3.0f, LN_EPS));
        t0[r] = d0 * rs;
        t1[r] = d1 * rs;
    }

    // ---- fused MLP: logits in log2 domain ----
    float l[4][3];
    {
        const float B0 = ws[96], B1 = ws[97], B2 = ws[98];
#pragma unroll
        for (int r = 0; r < 4; ++r) { l[r][0] = B0; l[r][1] = B1; l[r][2] = B2; }
    }
#pragma unroll
    for (int j = 0; j < 16; ++j) {
        const float A0 = ws[j];
        const float A1 = ws[16+j];
        const float nC = ws[32+j];
        const float u0 = ws[48+j];
        const float u1 = ws[64+j];
        const float u2 = ws[80+j];
#pragma unroll
        for (int r = 0; r < 4; ++r) {
            float a = fmaf(A1, t1[r], A0 * t0[r]);
            float m = fmaxf(a, nC);
            l[r][0] = fmaf(m, u0, l[r][0]);
            l[r][1] = fmaf(m, u1, l[r][1]);
            l[r][2] = fmaf(m, u2, l[r][2]);
        }
    }

    // ---- softmax (exp2, no max-subtract) + weighted sum ----
    float O[4];
#pragma unroll
    for (int r = 0; r < 4; ++r) {
        float e0 = __builtin_amdgcn_exp2f(l[r][0]);
        float e1 = __builtin_amdgcn_exp2f(l[r][1]);
        float e2 = __builtin_amdgcn_exp2f(l[r][2]);
        float rc = __builtin_amdgcn_rcpf(e0 + e1 + e2);
        O[r] = fmaf(X[r][0], e0, fmaf(X[r][1], e1, X[r][2] * e2)) * rc;
    }

    if (full) {
        vf4 o; o.x=O[0]; o.y=O[1]; o.z=O[2]; o.w=O[3];
        __builtin_nontemporal_store(o, &reinterpret_cast<vf4*>(out)[g]);
    } else {
        for (int r = 0; r < 4 && base + r < nrows; ++r) out[base + r] = O[r];
    }
}

// Fallback (ws too small): self-contained, weights via point-of-use s_loads.
__global__ __launch_bounds__(256) void nn2_fallback(
    const float* __restrict__ x,
    const float* __restrict__ lnw_g, const float* __restrict__ lnb_g,
    const float* __restrict__ w1_g,  const float* __restrict__ b1_g,
    const float* __restrict__ w2_g,  const float* __restrict__ b2_g,
    float* __restrict__ out, int nrows)
{
    int g = blockIdx.x * blockDim.x + threadIdx.x;
    long long base = (long long)g * 4;
    if (base >= nrows) return;
    const float lw0 = lnw_g[0], lw1 = lnw_g[1], lw2 = lnw_g[2];
    const float lb0 = lnb_g[0], lb1 = lnb_g[1], lb2 = lnb_g[2];
    float X[4][3];
    if (base + 4 <= nrows) {
        const float4* x4 = reinterpret_cast<const float4*>(x) + (long long)g * 3;
        float4 va = x4[0], vb = x4[1], vc = x4[2];
        X[0][0]=va.x; X[0][1]=va.y; X[0][2]=va.z;
        X[1][0]=va.w; X[1][1]=vb.x; X[1][2]=vb.y;
        X[2][0]=vb.z; X[2][1]=vb.w; X[2][2]=vc.x;
        X[3][0]=vc.y; X[3][1]=vc.z; X[3][2]=vc.w;
    } else {
        for (int r = 0; r < 4; ++r) {
            long long rr = (base + r < nrows) ? base + r : (long long)nrows - 1;
            X[r][0]=x[rr*3]; X[r][1]=x[rr*3+1]; X[r][2]=x[rr*3+2];
        }
    }
    float H[4][3];
#pragma unroll
    for (int r = 0; r < 4; ++r) {
        float x0=X[r][0], x1=X[r][1], x2=X[r][2];
        float mu=(x0+x1+x2)*(1.0f/3.0f);
        float d0=mu-x0, d1=mu-x1, d2=mu-x2;
        float rs=__builtin_amdgcn_rsqf(fmaf(fmaf(d0,d0,fmaf(d1,d1,d2*d2)),1.0f/3.0f,LN_EPS));
        H[r][0]=fmaf(d0*rs,lw0,lb0); H[r][1]=fmaf(d1*rs,lw1,lb1); H[r][2]=fmaf(d2*rs,lw2,lb2);
    }
    float L[4][3];
    { const float b20=b2_g[0],b21=b2_g[1],b22=b2_g[2];
#pragma unroll
      for (int r=0;r<4;++r){L[r][0]=b20;L[r][1]=b21;L[r][2]=b22;} }
#pragma unroll
    for (int j = 0; j < 16; ++j) {
        const float a0=w1_g[3*j],a1=w1_g[3*j+1],a2=w1_g[3*j+2],bj=b1_g[j];
        const float u0=w2_g[j],u1=w2_g[16+j],u2=w2_g[32+j];
#pragma unroll
        for (int r=0;r<4;++r){
            float hj=fmaf(H[r][2],a2,fmaf(H[r][1],a1,fmaf(H[r][0],a0,bj)));
            hj=fmaxf(hj,0.0f);
            L[r][0]=fmaf(hj,u0,L[r][0]); L[r][1]=fmaf(hj,u1,L[r][1]); L[r][2]=fmaf(hj,u2,L[r][2]);
        }
    }
    float O[4];
#pragma unroll
    for (int r=0;r<4;++r){
        float l0=L[r][0],l1=L[r][1],l2=L[r][2];
        float lm=fmaxf(l0,fmaxf(l1,l2));
        float s0=__expf(l0-lm),s1=__expf(l1-lm),s2=__expf(l2-lm);
        float rc=__builtin_amdgcn_rcpf(s0+s1+s2);
        O[r]=fmaf(X[r][0],s0,fmaf(X[r][1],s1,X[r][2]*s2))*rc;
    }
    if (base + 4 <= nrows) {
        float4 o; o.x=O[0];o.y=O[1];o.z=O[2];o.w=O[3];
        reinterpret_cast<float4*>(out)[g] = o;
    } else {
        for (int r = 0; r < 4 && base + r < nrows; ++r) out[base + r] = O[r];
    }
}

extern "C" void kernel_launch(void* const* d_in, const int* in_sizes, int n_in,
                              void* d_out, int out_size, void* d_ws, size_t ws_size,
                              hipStream_t stream) {
    const float* x    = (const float*)d_in[0];
    const float* lnw  = (const float*)d_in[1];
    const float* lnb  = (const float*)d_in[2];
    const float* w1   = (const float*)d_in[3];
    const float* b1   = (const float*)d_in[4];
    const float* w2   = (const float*)d_in[5];
    const float* b2   = (const float*)d_in[6];
    // d_in[7] (log_tau) is mathematically dead: softmin cancels in LayerNorm.
    float* out = (float*)d_out;
    int nrows = out_size;

    if (ws_size >= 99 * sizeof(float)) {
        float* ws = (float*)d_ws;
        nn2_setup<<<1, 64, 0, stream>>>(lnw, lnb, w1, b1, w2, b2, ws);
        int T    = (nrows + 3) / 4;            // 4 rows per thread
        int grid = (T + 255) / 256;
        nn2_main<<<grid, 256, 0, stream>>>(x, ws, out, nrows);
    } else {
        int ngroups = (nrows + 3) / 4;
        int grid    = (ngroups + 255) / 256;
        nn2_fallback<<<grid, 256, 0, stream>>>(x, lnw, lnb, w1, b1, w2, b2, out, nrows);
    }
}

// Round 8
// 49.198 us; speedup vs baseline: 3.9507x; 1.3291x over previous
//
#include <hip/hip_runtime.h>
#include <math.h>

typedef float vf4 __attribute__((ext_vector_type(4)));

#define LN_EPS 1e-5f
#define NBINS  1024   // LUT nodes over diamond-angle v in [-1,3); node i at v = i/256 - 1

// ============================================================================
// KEY IDENTITY (R8): LayerNorm(3) output t = d*rsqrt(var+eps) satisfies
// sum(t)=0, ||t||^2 = 3*var/(var+eps) ~= 3  ==> ONE degree of freedom.
// The softmax weights are w(theta) only, where theta is the direction of
//   (P,Q) = (sqrt3*(x1-x0), 2*x2-x0-x1)            [orthonormal plane coords]
// Hot path: diamond-angle v from (P,Q) (1 rcp, no rsqrt/LN), 1024-node LDS
// LUT + lerp, blend with x. eps-radius error bounded <=~4e-3 (err = |sum
// dw_i*d_i| <= ||dw||*sqrt(ssq), maximized at var~eps); lerp error <=~3e-3.
// Setup kernel builds the LUT exactly from the raw weights (no folding).
// ============================================================================

__global__ void nn2_lut_setup(const float* __restrict__ lnw, const float* __restrict__ lnb,
                              const float* __restrict__ w1,  const float* __restrict__ b1,
                              const float* __restrict__ w2,  const float* __restrict__ b2,
                              float* __restrict__ ws)
{
    int i = blockIdx.x * blockDim.x + threadIdx.x;
    if (i >= NBINS) return;
    // invert diamond angle: v -> (P,Q) with |P|+|Q|=1
    float v  = (float)i * (4.0f / NBINS) - 1.0f;
    float dd = (v <= 1.0f) ? v : (2.0f - v);
    float Pm = 1.0f - fabsf(dd);
    float P  = (v <= 1.0f) ? Pm : -Pm;
    float Q  = dd;
    // direction -> point on the LN circle (radius sqrt(3))
    float n = rsqrtf(P * P + Q * Q);
    float p = 1.7320508075688772f * P * n;
    float q = 1.7320508075688772f * Q * n;
    const float is2 = 0.7071067811865476f;   // 1/sqrt2
    const float is6 = 0.4082482904638631f;   // 1/sqrt6
    float t0 =  p * is2 + q * is6;
    float t1 = -p * is2 + q * is6;
    float t2 = -2.0f * q * is6;
    // exact LN-affine -> MLP -> softmax at this node
    float h0 = t0 * lnw[0] + lnb[0];
    float h1 = t1 * lnw[1] + lnb[1];
    float h2 = t2 * lnw[2] + lnb[2];
    float l0 = b2[0], l1 = b2[1], l2 = b2[2];
    for (int j = 0; j < 16; ++j) {
        float a = fmaf(w1[3*j], h0, fmaf(w1[3*j+1], h1, fmaf(w1[3*j+2], h2, b1[j])));
        a = fmaxf(a, 0.0f);
        l0 = fmaf(w2[j],    a, l0);
        l1 = fmaf(w2[16+j], a, l1);
        l2 = fmaf(w2[32+j], a, l2);
    }
    float m  = fmaxf(l0, fmaxf(l1, l2));
    float e0 = expf(l0 - m), e1 = expf(l1 - m), e2 = expf(l2 - m);
    float r  = 1.0f / (e0 + e1 + e2);
    ws[i]           = e0 * r;   // SoA: w0 | w1 | w2
    ws[NBINS + i]   = e1 * r;
    ws[2*NBINS + i] = e2 * r;
}

__device__ __forceinline__ float row_out(float x0, float x1, float x2,
                                         const float* __restrict__ lut)
{
    float P   = (x1 - x0) * 1.7320508075688772f;
    float Q   = fmaf(2.0f, x2, -(x0 + x1));
    float den = fabsf(P) + fabsf(Q) + 1e-20f;
    float dd  = Q * __builtin_amdgcn_rcpf(den);
    float v   = (P >= 0.0f) ? dd : (2.0f - dd);
    float u   = fmaf(v, 256.0f, 256.0f);          // [0,1024]
    int   iu  = (int)u;
    float f   = u - (float)iu;
    int i0 = iu & (NBINS - 1);
    int i1 = (iu + 1) & (NBINS - 1);               // periodic wrap (v=3 == v=-1)
    float a0 = lut[i0],           b0 = lut[i1];
    float a1 = lut[NBINS + i0],   b1 = lut[NBINS + i1];
    float a2 = lut[2*NBINS + i0], b2 = lut[2*NBINS + i1];
    float w0 = fmaf(f, b0 - a0, a0);
    float w1 = fmaf(f, b1 - a1, a1);
    float w2 = fmaf(f, b2 - a2, a2);
    return fmaf(x0, w0, fmaf(x1, w1, x2 * w2));
}

__global__ __launch_bounds__(256) void nn2_lut_main(
    const float* __restrict__ x, const float* __restrict__ ws,
    float* __restrict__ out, int nrows, int pthreads)
{
    __shared__ float lut[3 * NBINS];               // 12 KB -> 8 blocks/CU OK
    int tid = threadIdx.x;
#pragma unroll
    for (int k = 0; k < (3 * NBINS) / 256; ++k)
        lut[tid + 256 * k] = ws[tid + 256 * k];
    __syncthreads();

    long long T = ((long long)nrows + 3) >> 2;     // 4-row groups
    const vf4* x4 = reinterpret_cast<const vf4*>(x);
    vf4* out4 = reinterpret_cast<vf4*>(out);

    for (long long grp = (long long)blockIdx.x * blockDim.x + tid; grp < T;
         grp += pthreads) {
        long long base = grp * 4;
        float X[4][3];
        bool full = (base + 4 <= nrows);
        if (full) {
            vf4 va = x4[grp*3 + 0], vb = x4[grp*3 + 1], vc = x4[grp*3 + 2];
            X[0][0]=va.x; X[0][1]=va.y; X[0][2]=va.z;
            X[1][0]=va.w; X[1][1]=vb.x; X[1][2]=vb.y;
            X[2][0]=vb.z; X[2][1]=vb.w; X[2][2]=vc.x;
            X[3][0]=vc.y; X[3][1]=vc.z; X[3][2]=vc.w;
        } else {
#pragma unroll
            for (int r = 0; r < 4; ++r) {
                long long rr = (base + r < nrows) ? base + r : (long long)nrows - 1;
                X[r][0]=x[rr*3]; X[r][1]=x[rr*3+1]; X[r][2]=x[rr*3+2];
            }
        }
        float O[4];
#pragma unroll
        for (int r = 0; r < 4; ++r)
            O[r] = row_out(X[r][0], X[r][1], X[r][2], lut);

        if (full) {
            vf4 o; o.x=O[0]; o.y=O[1]; o.z=O[2]; o.w=O[3];
            __builtin_nontemporal_store(o, &out4[grp]);
        } else {
            for (int r = 0; r < 4 && base + r < nrows; ++r) out[base + r] = O[r];
        }
    }
}

// Fallback (ws too small): exact self-contained path (R7-proven).
__global__ __launch_bounds__(256) void nn2_fallback(
    const float* __restrict__ x,
    const float* __restrict__ lnw_g, const float* __restrict__ lnb_g,
    const float* __restrict__ w1_g,  const float* __restrict__ b1_g,
    const float* __restrict__ w2_g,  const float* __restrict__ b2_g,
    float* __restrict__ out, int nrows)
{
    int g = blockIdx.x * blockDim.x + threadIdx.x;
    long long base = (long long)g * 4;
    if (base >= nrows) return;
    const float lw0 = lnw_g[0], lw1 = lnw_g[1], lw2 = lnw_g[2];
    const float lb0 = lnb_g[0], lb1 = lnb_g[1], lb2 = lnb_g[2];
    float X[4][3];
    if (base + 4 <= nrows) {
        const float4* x4 = reinterpret_cast<const float4*>(x) + (long long)g * 3;
        float4 va = x4[0], vb = x4[1], vc = x4[2];
        X[0][0]=va.x; X[0][1]=va.y; X[0][2]=va.z;
        X[1][0]=va.w; X[1][1]=vb.x; X[1][2]=vb.y;
        X[2][0]=vb.z; X[2][1]=vb.w; X[2][2]=vc.x;
        X[3][0]=vc.y; X[3][1]=vc.z; X[3][2]=vc.w;
    } else {
        for (int r = 0; r < 4; ++r) {
            long long rr = (base + r < nrows) ? base + r : (long long)nrows - 1;
            X[r][0]=x[rr*3]; X[r][1]=x[rr*3+1]; X[r][2]=x[rr*3+2];
        }
    }
    float H[4][3];
#pragma unroll
    for (int r = 0; r < 4; ++r) {
        float x0=X[r][0], x1=X[r][1], x2=X[r][2];
        float mu=(x0+x1+x2)*(1.0f/3.0f);
        float d0=mu-x0, d1=mu-x1, d2=mu-x2;
        float rs=__builtin_amdgcn_rsqf(fmaf(fmaf(d0,d0,fmaf(d1,d1,d2*d2)),1.0f/3.0f,LN_EPS));
        H[r][0]=fmaf(d0*rs,lw0,lb0); H[r][1]=fmaf(d1*rs,lw1,lb1); H[r][2]=fmaf(d2*rs,lw2,lb2);
    }
    float L[4][3];
    { const float b20=b2_g[0],b21=b2_g[1],b22=b2_g[2];
#pragma unroll
      for (int r=0;r<4;++r){L[r][0]=b20;L[r][1]=b21;L[r][2]=b22;} }
#pragma unroll
    for (int j = 0; j < 16; ++j) {
        const float a0=w1_g[3*j],a1=w1_g[3*j+1],a2=w1_g[3*j+2],bj=b1_g[j];
        const float u0=w2_g[j],u1=w2_g[16+j],u2=w2_g[32+j];
#pragma unroll
        for (int r=0;r<4;++r){
            float hj=fmaf(H[r][2],a2,fmaf(H[r][1],a1,fmaf(H[r][0],a0,bj)));
            hj=fmaxf(hj,0.0f);
            L[r][0]=fmaf(hj,u0,L[r][0]); L[r][1]=fmaf(hj,u1,L[r][1]); L[r][2]=fmaf(hj,u2,L[r][2]);
        }
    }
    float O[4];
#pragma unroll
    for (int r=0;r<4;++r){
        float l0=L[r][0],l1=L[r][1],l2=L[r][2];
        float lm=fmaxf(l0,fmaxf(l1,l2));
        float s0=__expf(l0-lm),s1=__expf(l1-lm),s2=__expf(l2-lm);
        float rc=__builtin_amdgcn_rcpf(s0+s1+s2);
        O[r]=fmaf(X[r][0],s0,fmaf(X[r][1],s1,X[r][2]*s2))*rc;
    }
    if (base + 4 <= nrows) {
        float4 o; o.x=O[0];o.y=O[1];o.z=O[2];o.w=O[3];
        reinterpret_cast<float4*>(out)[g] = o;
    } else {
        for (int r = 0; r < 4 && base + r < nrows; ++r) out[base + r] = O[r];
    }
}

extern "C" void kernel_launch(void* const* d_in, const int* in_sizes, int n_in,
                              void* d_out, int out_size, void* d_ws, size_t ws_size,
                              hipStream_t stream) {
    const float* x    = (const float*)d_in[0];
    const float* lnw  = (const float*)d_in[1];
    const float* lnb  = (const float*)d_in[2];
    const float* w1   = (const float*)d_in[3];
    const float* b1   = (const float*)d_in[4];
    const float* w2   = (const float*)d_in[5];
    const float* b2   = (const float*)d_in[6];
    // d_in[7] (log_tau): softmin cancels exactly inside LayerNorm -> unused.
    float* out = (float*)d_out;
    int nrows = out_size;

    if (ws_size >= (size_t)(3 * NBINS) * sizeof(float)) {
        float* ws = (float*)d_ws;
        nn2_lut_setup<<<NBINS / 256, 256, 0, stream>>>(lnw, lnb, w1, b1, w2, b2, ws);
        long long T = ((long long)nrows + 3) / 4;
        int grid = 2048;
        long long need = (T + 255) / 256;
        if (need < grid) grid = (int)need;
        int pthreads = grid * 256;
        nn2_lut_main<<<grid, 256, 0, stream>>>(x, ws, out, nrows, pthreads);
    } else {
        int ngroups = (nrows + 3) / 4;
        int grid    = (ngroups + 255) / 256;
        nn2_fallback<<<grid, 256, 0, stream>>>(x, lnw, lnb, w1, b1, w2, b2, out, nrows);
    }
}